// Round 11
// baseline (292.502 us; speedup 1.0000x reference)
//
#include <hip/hip_runtime.h>
#include <cstdint>
#include <cstddef>

// DeformConv2d B=8 C=256 H=W=64 Cout=256 K=3 s=1 p=1 d=1
// Round 11 = Round 9 base (proven 110us) + ONE change: wave tiling
//  16 waves = 4 cg x 4 pg, wave tile 64co x 16px. Per k-step each wave
//  reads 1 LDS b128 (bf) + 4 global b128 (af, L2-hot weights) instead of
//  r9's 4 LDS b128 + 1 global -> MFMA-phase LDS port traffic / 4.
//  Everything else (staging, tables, barriers, PADK) identical to r9.
// Fallback (ws too small): round-6 proven kernel.

#define B_   8
#define C_   256
#define H_   64
#define W_   64
#define CO_  256
#define KK_  9
#define PADK 296             // padded k row (bf16): 592B rows = 37x16B (odd)

typedef short  short8   __attribute__((ext_vector_type(8)));
typedef float  f32x4    __attribute__((ext_vector_type(4)));
typedef float  f32x2    __attribute__((ext_vector_type(2)));

__device__ inline short f2bf(float f) {   // round-to-nearest-even fp32->bf16
    uint32_t u = __builtin_bit_cast(uint32_t, f);
    u += 0x7FFFu + ((u >> 16) & 1u);
    return (short)(u >> 16);
}
__device__ inline float bf2f(short s) {
    return __builtin_bit_cast(float, (uint32_t)(uint16_t)s << 16);
}

// ---- prepass 1: weight fp32 -> bf16, permuted [co][ch(32c)][kk][c_l] ----
__global__ __launch_bounds__(256) void wperm_k(const float* __restrict__ w,
                                               short* __restrict__ wp) {
    const int i = blockIdx.x * 256 + threadIdx.x;   // 73728 octet tasks
    const int q  = i & 3;                // c_l octet
    const int kk = (i >> 2) % 9;
    const int ch = ((i >> 2) / 9) & 7;
    const int co = i / 288;
    short8 v;
#pragma unroll
    for (int j = 0; j < 8; ++j)
        v[j] = f2bf(w[((size_t)(co * C_) + ch * 32 + q * 8 + j) * KK_ + kk]);
    *reinterpret_cast<short8*>(wp + (size_t)i * 8) = v;
}

// ---- prepass 2: x NCHW fp32 -> NHWC bf16 ----
__global__ __launch_bounds__(256) void xpose(const float* __restrict__ x,
                                             short* __restrict__ xT) {
    __shared__ short tile[64 * 258];     // [xw][c], +2 pad vs bank conflicts
    const int bid = blockIdx.x;          // 512 = 64*8
    const int y = bid & 63;
    const int b = bid >> 6;
    const int t = threadIdx.x;
    const int c4 = t >> 6;               // 0..3 (wave-uniform)
    const int xw = t & 63;
    const float* src = x + (size_t)b * (C_ * H_ * W_) + (size_t)y * W_ + xw;
#pragma unroll 8
    for (int j = 0; j < 64; ++j) {
        const int c = j * 4 + c4;
        tile[xw * 258 + c] = f2bf(src[(size_t)c * (H_ * W_)]);
    }
    __syncthreads();
    short* dst = xT + ((size_t)(b * (H_ * W_)) + y * W_) * C_;
#pragma unroll
    for (int r = 0; r < 8; ++r) {
        const int idx = r * 256 + t;     // 0..2047 short8 groups
        const int xw2 = idx >> 5;
        const int c2  = (idx & 31) * 8;
        *reinterpret_cast<short8*>(dst + xw2 * C_ + c2) =
            *reinterpret_cast<const short8*>(&tile[xw2 * 258 + c2]);
    }
}

// ---- main: fused im2col (NHWC gathers) + MFMA, 64co x 16px wave tiles ----
__global__ __launch_bounds__(1024, 8) void dcn_mfma5(
    const short* __restrict__ xT,      // [b][y][x][c] bf16, 2MB/batch
    const float* __restrict__ offset,
    const short* __restrict__ wpm,     // [co][ch][kk][c_l] bf16
    const float* __restrict__ bias,
    float* __restrict__ out)
{
    __shared__ uint32_t t_pA[KK_ * 64];  // idx00 | idx01<<16  (pixel indices)
    __shared__ uint32_t t_pB[KK_ * 64];  // idx10 | idx11<<16
    __shared__ f32x4    t_wv[KK_ * 64];  // 4 corner weights (0 if invalid)
    __shared__ short    cols[64 * PADK]; // [px][k'] k' = kk*32 + c_l

    const int bid = blockIdx.x;          // 512
    const int b   = bid & 7;             // wgid%8 -> XCD affinity for batch
    const int ho  = bid >> 3;

    const int t    = threadIdx.x;
    const int lane = t & 63;
    const int wave = t >> 6;             // 0..15

    // ---- bilinear tables: one entry per (kk, wo) ----
    if (t < KK_ * 64) {
        const int e  = t;
        const int kk = e >> 6;
        const int wo = e & 63;
        const int ky = kk / 3, kx = kk % 3;
        const float offy = offset[(((b * 18) + kk * 2 + 0) * 64 + ho) * 64 + wo];
        const float offx = offset[(((b * 18) + kk * 2 + 1) * 64 + ho) * 64 + wo];
        const float py  = (float)(ho - 1 + ky) + offy;
        const float pxx = (float)(wo - 1 + kx) + offx;
        const float y0f = floorf(py), x0f = floorf(pxx);
        const float wy = py - y0f, wx = pxx - x0f;
        const int y0 = (int)y0f, x0 = (int)x0f;
        const int y1 = y0 + 1,   x1 = x0 + 1;
        const float vy0 = (y0 >= 0 && y0 < H_) ? 1.f : 0.f;
        const float vy1 = (y1 >= 0 && y1 < H_) ? 1.f : 0.f;
        const float vx0 = (x0 >= 0 && x0 < W_) ? 1.f : 0.f;
        const float vx1 = (x1 >= 0 && x1 < W_) ? 1.f : 0.f;
        f32x4 wv;
        wv[0] = (1.f - wy) * (1.f - wx) * vy0 * vx0;
        wv[1] = (1.f - wy) * wx         * vy0 * vx1;
        wv[2] = wy         * (1.f - wx) * vy1 * vx0;
        wv[3] = wy         * wx         * vy1 * vx1;
        const int y0c = min(max(y0, 0), H_ - 1);
        const int y1c = min(max(y1, 0), H_ - 1);
        const int x0c = min(max(x0, 0), W_ - 1);
        const int x1c = min(max(x1, 0), W_ - 1);
        t_pA[e] = (uint32_t)(y0c * W_ + x0c) | ((uint32_t)(y0c * W_ + x1c) << 16);
        t_pB[e] = (uint32_t)(y1c * W_ + x0c) | ((uint32_t)(y1c * W_ + x1c) << 16);
        t_wv[e] = wv;
    }
    __syncthreads();

    f32x4 acc[4];                        // [mt] 16co slices
#pragma unroll
    for (int i = 0; i < 4; ++i) acc[i] = (f32x4)0.f;

    const int cg = wave & 3;             // co-64 group
    const int pg = wave >> 2;            // px-16 group
    const int co0 = __builtin_amdgcn_readfirstlane(cg * 64);
    const int px0 = __builtin_amdgcn_readfirstlane(pg * 16);
    const int m_l = lane & 15;
    const int k_l = (lane >> 4) << 3;

    // weight base for this lane's A-rows: co = co0 + mt*16 + m_l
    const short* wr = wpm + (size_t)(co0 + m_l) * (C_ * KK_);

    // staging ids: thread -> (px, ch-octet, tap-replica)  [identical to r9]
    const int soct = t & 3;              // channel octet (8 ch)
    const int spx  = (t >> 2) & 63;      // px
    const int srep = t >> 8;             // 0..3: taps {srep, srep+4, srep+8}
    const char* xq = (const char*)xT + ((size_t)b << 21) + soct * 16;

    for (int ch = 0; ch < 8; ++ch) {
        // ---- stage: 4 coalesced 16B corner loads per tap ----
        const char* xc = xq + ch * 64;
#pragma unroll
        for (int jj = 0; jj < 3; ++jj) {
            const int kk = srep + jj * 4;
            if (kk < KK_) {
                const int e  = kk * 64 + spx;
                const uint32_t pA = t_pA[e];
                const uint32_t pB = t_pB[e];
                const f32x4    wv = t_wv[e];
                short8 s00, s01, s10, s11;
                __builtin_memcpy(&s00, xc + (size_t)(pA & 0xFFFFu) * 512, 16);
                __builtin_memcpy(&s01, xc + (size_t)(pA >> 16)     * 512, 16);
                __builtin_memcpy(&s10, xc + (size_t)(pB & 0xFFFFu) * 512, 16);
                __builtin_memcpy(&s11, xc + (size_t)(pB >> 16)     * 512, 16);
                short8 vs;
#pragma unroll
                for (int j = 0; j < 8; ++j) {
                    const float v = wv[0] * bf2f(s00[j]) + wv[1] * bf2f(s01[j])
                                  + wv[2] * bf2f(s10[j]) + wv[3] * bf2f(s11[j]);
                    vs[j] = f2bf(v);
                }
                *reinterpret_cast<short8*>(
                    &cols[spx * PADK + kk * 32 + soct * 8]) = vs;
            }
        }
        __syncthreads();

        // ---- MFMA over 9 k-steps: 1 LDS bf read + 4 global af reads ----
#pragma unroll
        for (int s = 0; s < 9; ++s) {
            const int krow = s * 32 + k_l;
            const short8 bf = *reinterpret_cast<const short8*>(
                &cols[(px0 + m_l) * PADK + krow]);
            const int kg = ch * 288 + krow;
#pragma unroll
            for (int mt = 0; mt < 4; ++mt) {
                short8 af;
                __builtin_memcpy(&af, wr + (size_t)mt * 16 * (C_ * KK_) + kg, 16);
                acc[mt] = __builtin_amdgcn_mfma_f32_16x16x32_bf16(
                    af, bf, acc[mt], 0, 0, 0);
            }
        }
        __syncthreads();
    }

    // ---- epilogue: D mapping col=lane&15 (px), row=(lane>>4)*4+r (co) ----
    const int r0 = (lane >> 4) << 2;
#pragma unroll
    for (int mt = 0; mt < 4; ++mt) {
#pragma unroll
        for (int r = 0; r < 4; ++r) {
            const int co = co0 + mt * 16 + r0 + r;
            out[((size_t)(b * CO_ + co) * H_ + ho) * W_ + px0 + m_l]
                = acc[mt][r] + bias[co];
        }
    }
}

// ================= fallback (round-6 proven path, ws < 18 MB) =================
__global__ __launch_bounds__(256) void w2bf_fb(const float* __restrict__ w,
                                               short* __restrict__ wb, int n8) {
    const int i = blockIdx.x * 256 + threadIdx.x;
    if (i >= n8) return;
    const f32x4 a = *reinterpret_cast<const f32x4*>(w + (size_t)i * 8);
    const f32x4 bq = *reinterpret_cast<const f32x4*>(w + (size_t)i * 8 + 4);
    short8 v;
#pragma unroll
    for (int j = 0; j < 4; ++j) { v[j] = f2bf(a[j]); v[j + 4] = f2bf(bq[j]); }
    *reinterpret_cast<short8*>(wb + (size_t)i * 8) = v;
}

__global__ __launch_bounds__(512, 2) void dcn_mfma_fb(
    const float* __restrict__ x,
    const float* __restrict__ offset,
    const short* __restrict__ wbf,
    const float* __restrict__ bias,
    float* __restrict__ out)
{
    __shared__ uint32_t t_oab[KK_ * 64];
    __shared__ f32x4    t_wv[KK_ * 64];
    __shared__ short    colsf[64 * PADK];

    const int bid = blockIdx.x;
    const int ho  = bid & 63;
    const int b   = bid >> 6;
    const int t    = threadIdx.x;
    const int lane = t & 63;
    const int wave = t >> 6;

    for (int e = t; e < KK_ * 64; e += 512) {
        const int kk = e >> 6;
        const int wo = e & 63;
        const int ky = kk / 3, kx = kk % 3;
        const float offy = offset[(((b * 18) + kk * 2 + 0) * 64 + ho) * 64 + wo];
        const float offx = offset[(((b * 18) + kk * 2 + 1) * 64 + ho) * 64 + wo];
        const float py  = (float)(ho - 1 + ky) + offy;
        const float pxx = (float)(wo - 1 + kx) + offx;
        const float y0f = floorf(py), x0f = floorf(pxx);
        const float wy = py - y0f, wx = pxx - x0f;
        const int y0 = (int)y0f, x0 = (int)x0f;
        const int y1 = y0 + 1,   x1 = x0 + 1;
        const float vy0 = (y0 >= 0 && y0 < H_) ? 1.f : 0.f;
        const float vy1 = (y1 >= 0 && y1 < H_) ? 1.f : 0.f;
        const float vx0 = (x0 >= 0 && x0 < W_) ? 1.f : 0.f;
        const float vx1 = (x1 >= 0 && x1 < W_) ? 1.f : 0.f;
        const float wv0 = (1.f - wy) * (1.f - wx) * vy0 * vx0;
        const float wv1 = (1.f - wy) * wx         * vy0 * vx1;
        const float wv2 = wy         * (1.f - wx) * vy1 * vx0;
        const float wv3 = wy         * wx         * vy1 * vx1;
        const int y0c = min(max(y0, 0), H_ - 1);
        const int y1c = min(max(y1, 0), H_ - 1);
        const int x0c = min(max(x0, 0), W_ - 1);
        const int x1c = min(max(x1, 0), W_ - 1);
        const int pb  = min(max(x0, 0), W_ - 2);
        const float sA0 = (x0c == pb)     ? 1.f : 0.f;
        const float sB0 = (x1c == pb)     ? 1.f : 0.f;
        const float sA1 = (x0c == pb + 1) ? 1.f : 0.f;
        const float sB1 = (x1c == pb + 1) ? 1.f : 0.f;
        f32x4 wv;
        wv[0] = sA0 * wv0 + sB0 * wv1;
        wv[1] = sA1 * wv0 + sB1 * wv1;
        wv[2] = sA0 * wv2 + sB0 * wv3;
        wv[3] = sA1 * wv2 + sB1 * wv3;
        t_oab[e] = (uint32_t)((y0c * W_ + pb) * 4) |
                   ((uint32_t)((y1c * W_ + pb) * 4) << 16);
        t_wv[e] = wv;
    }
    __syncthreads();

    f32x4 acc[4][2];
#pragma unroll
    for (int i = 0; i < 4; ++i) { acc[i][0] = (f32x4)0.f; acc[i][1] = (f32x4)0.f; }

    const int wm = wave >> 1;
    const int wn = wave & 1;
    const int co0 = __builtin_amdgcn_readfirstlane(wm * 64);
    const int px0 = __builtin_amdgcn_readfirstlane(wn * 32);
    const int wqs = __builtin_amdgcn_readfirstlane(wave);
    const int m_l = lane & 15;
    const int k_l = (lane >> 4) << 3;

    const short* wrow[4];
#pragma unroll
    for (int mt = 0; mt < 4; ++mt)
        wrow[mt] = wbf + (size_t)(co0 + mt * 16 + m_l) * (C_ * KK_);

    for (int c0 = 0; c0 < C_; c0 += 32) {
        const char* xp[4];
#pragma unroll
        for (int dc = 0; dc < 4; ++dc)
            xp[dc] = (const char*)(x + ((size_t)(b * C_ + c0 + 4 * wqs + dc) << 12));
#pragma unroll
        for (int j = 0; j < 9; ++j) {
            short vs[4];
#pragma unroll
            for (int jj = 0; jj < 4; ++jj) {
                const int idx = j * 4 + jj;
                const int dc  = idx / 9;
                const int kk  = idx % 9;
                const uint32_t oab = t_oab[kk * 64 + lane];
                const f32x4    wv  = t_wv[kk * 64 + lane];
                f32x2 lo, hi;
                __builtin_memcpy(&lo, xp[dc] + (oab & 0xFFFFu), 8);
                __builtin_memcpy(&hi, xp[dc] + (oab >> 16), 8);
                vs[jj] = f2bf(wv[0] * lo[0] + wv[1] * lo[1] +
                              wv[2] * hi[0] + wv[3] * hi[1]);
            }
            short* cw = &colsf[lane * PADK + (wave * 9 + j) * 4];
            cw[0] = vs[0]; cw[1] = vs[1]; cw[2] = vs[2]; cw[3] = vs[3];
        }
        __syncthreads();
#pragma unroll
        for (int s = 0; s < 9; ++s) {
            const int krow = s * 32 + k_l;
            const short8 bfA = *reinterpret_cast<const short8*>(
                &colsf[(px0 + m_l) * PADK + krow]);
            const short8 bfB = *reinterpret_cast<const short8*>(
                &colsf[(px0 + 16 + m_l) * PADK + krow]);
            const int kglob = c0 * 9 + krow;
#pragma unroll
            for (int mt = 0; mt < 4; ++mt) {
                const short8 af = *reinterpret_cast<const short8*>(wrow[mt] + kglob);
                acc[mt][0] = __builtin_amdgcn_mfma_f32_16x16x32_bf16(
                    af, bfA, acc[mt][0], 0, 0, 0);
                acc[mt][1] = __builtin_amdgcn_mfma_f32_16x16x32_bf16(
                    af, bfB, acc[mt][1], 0, 0, 0);
            }
        }
        __syncthreads();
    }

    const int r0 = (lane >> 4) << 2;
#pragma unroll
    for (int mt = 0; mt < 4; ++mt) {
#pragma unroll
        for (int r = 0; r < 4; ++r) {
            const int co = co0 + mt * 16 + r0 + r;
            const float bv = bias[co];
            float* orow = out + ((size_t)(b * CO_ + co) * H_ + ho) * W_;
            orow[px0 + m_l]      = acc[mt][0][r] + bv;
            orow[px0 + 16 + m_l] = acc[mt][1][r] + bv;
        }
    }
}

extern "C" void kernel_launch(void* const* d_in, const int* in_sizes, int n_in,
                              void* d_out, int out_size, void* d_ws, size_t ws_size,
                              hipStream_t stream) {
    const float* x      = (const float*)d_in[0];
    const float* offset = (const float*)d_in[1];
    const float* weight = (const float*)d_in[2];
    const float* bias   = (const float*)d_in[3];
    float* out = (float*)d_out;
    (void)in_sizes; (void)n_in; (void)out_size;

    const size_t WPM_BYTES = (size_t)CO_ * C_ * KK_ * 2;          // 1,179,648
    const size_t XT_BYTES  = (size_t)B_ * H_ * W_ * C_ * 2;       // 16,777,216

    if (ws_size >= WPM_BYTES + XT_BYTES) {
        short* wpm = (short*)d_ws;
        short* xT  = (short*)((char*)d_ws + WPM_BYTES);
        hipLaunchKernelGGL(wperm_k, dim3(288), dim3(256), 0, stream, weight, wpm);
        hipLaunchKernelGGL(xpose,   dim3(512), dim3(256), 0, stream, x, xT);
        hipLaunchKernelGGL(dcn_mfma5, dim3(512), dim3(1024), 0, stream,
                           xT, offset, wpm, bias, out);
    } else {
        short* wbf = (short*)d_ws;   // 1.18 MB
        hipLaunchKernelGGL(w2bf_fb, dim3(288), dim3(256), 0, stream,
                           weight, wbf, 73728);
        hipLaunchKernelGGL(dcn_mfma_fb, dim3(512), dim3(512), 0, stream,
                           x, offset, wbf, bias, out);
    }
}

// Round 12
// 86.878 us; speedup vs baseline: 3.3668x; 3.3668x over previous
//
#include <hip/hip_runtime.h>
#include <cstdint>
#include <cstddef>

// DeformConv2d B=8 C=256 H=W=64 Cout=256 K=3 s=1 p=1 d=1
// Round 12 = Round 9 base (110us) + fragment-native layouts:
//  - cols stored in MFMA B-fragment order [pxfrag][kk][lane*16B]:
//    bf = ds_read_b128 of a contiguous 1KB/wave -> minimal bank pattern.
//  - weights pre-swizzled to A-fragment order [cofrag][ch][kk][lane*16B]:
//    af = fully coalesced 1KB global load.
//  - wave tile 32co x 32px (8 cog x 2 pxg, 2x2 fragments): per step
//    2 coalesced af + 2 LDS bf + 4 MFMA (halves LDS read instrs vs r9).
//  Staging / tables / gather identical to r9. Arithmetic bit-identical.
// Fallback (ws too small): round-6 proven kernel.

#define B_   8
#define C_   256
#define H_   64
#define W_   64
#define CO_  256
#define KK_  9

typedef short  short8   __attribute__((ext_vector_type(8)));
typedef float  f32x4    __attribute__((ext_vector_type(4)));
typedef float  f32x2    __attribute__((ext_vector_type(2)));

__device__ inline short f2bf(float f) {   // round-to-nearest-even fp32->bf16
    uint32_t u = __builtin_bit_cast(uint32_t, f);
    u += 0x7FFFu + ((u >> 16) & 1u);
    return (short)(u >> 16);
}
__device__ inline float bf2f(short s) {
    return __builtin_bit_cast(float, (uint32_t)(uint16_t)s << 16);
}

// ---- prepass 1: weight fp32 -> bf16 in A-FRAGMENT order ----
// entry i = ((cofrag*8 + ch)*9 + kk)*64 + lane ; each entry = 8 bf16 (16B)
// A-frag (16x16x32): lane holds A[row=lane&15][k=(lane>>4)*8+j]
// k within chunk = c_local = (lane>>4)*8 + j ; c = ch*32 + c_local
__global__ __launch_bounds__(256) void wperm_frag(const float* __restrict__ w,
                                                  short* __restrict__ wp) {
    const int i = blockIdx.x * 256 + threadIdx.x;   // 0..73727
    const int lane_w = i & 63;
    const int rest   = i >> 6;
    const int kk     = rest % 9;
    const int rest2  = rest / 9;
    const int ch     = rest2 & 7;
    const int cofrag = rest2 >> 3;                  // 0..15
    const int co     = cofrag * 16 + (lane_w & 15);
    const int cb     = ch * 32 + (lane_w >> 4) * 8;
    short8 v;
#pragma unroll
    for (int j = 0; j < 8; ++j)
        v[j] = f2bf(w[((size_t)co * C_ + cb + j) * KK_ + kk]);
    *reinterpret_cast<short8*>(wp + (size_t)i * 8) = v;
}

// ---- prepass 2: x NCHW fp32 -> NHWC bf16 ----
__global__ __launch_bounds__(256) void xpose(const float* __restrict__ x,
                                             short* __restrict__ xT) {
    __shared__ short tile[64 * 258];     // [xw][c], +2 pad vs bank conflicts
    const int bid = blockIdx.x;          // 512 = 64*8
    const int y = bid & 63;
    const int b = bid >> 6;
    const int t = threadIdx.x;
    const int c4 = t >> 6;               // 0..3 (wave-uniform)
    const int xw = t & 63;
    const float* src = x + (size_t)b * (C_ * H_ * W_) + (size_t)y * W_ + xw;
#pragma unroll 8
    for (int j = 0; j < 64; ++j) {
        const int c = j * 4 + c4;
        tile[xw * 258 + c] = f2bf(src[(size_t)c * (H_ * W_)]);
    }
    __syncthreads();
    short* dst = xT + ((size_t)(b * (H_ * W_)) + y * W_) * C_;
#pragma unroll
    for (int r = 0; r < 8; ++r) {
        const int idx = r * 256 + t;     // 0..2047 short8 groups
        const int xw2 = idx >> 5;
        const int c2  = (idx & 31) * 8;
        *reinterpret_cast<short8*>(dst + xw2 * C_ + c2) =
            *reinterpret_cast<const short8*>(&tile[xw2 * 258 + c2]);
    }
}

// ---- main ----
__global__ __launch_bounds__(1024, 8) void dcn_mfma6(
    const short* __restrict__ xT,      // [b][y][x][c] bf16, 2MB/batch
    const float* __restrict__ offset,
    const short* __restrict__ wfr,     // A-fragment-ordered bf16 weights
    const float* __restrict__ bias,
    float* __restrict__ out)
{
    __shared__ uint32_t t_pA[KK_ * 64];   // idx00 | idx01<<16
    __shared__ uint32_t t_pB[KK_ * 64];   // idx10 | idx11<<16
    __shared__ f32x4    t_wv[KK_ * 64];   // 4 corner weights (0 if invalid)
    __shared__ short    colsF[4 * 9 * 512];  // B-frag order [pxfrag][kk][1KB]

    const int bid = blockIdx.x;          // 512
    const int b   = bid & 7;             // wgid%8 -> XCD affinity for batch
    const int ho  = bid >> 3;

    const int t    = threadIdx.x;
    const int lane = t & 63;
    const int wave = t >> 6;             // 0..15

    // ---- bilinear tables: one entry per (kk, wo) ----
    if (t < KK_ * 64) {
        const int e  = t;
        const int kk = e >> 6;
        const int wo = e & 63;
        const int ky = kk / 3, kx = kk % 3;
        const float offy = offset[(((b * 18) + kk * 2 + 0) * 64 + ho) * 64 + wo];
        const float offx = offset[(((b * 18) + kk * 2 + 1) * 64 + ho) * 64 + wo];
        const float py  = (float)(ho - 1 + ky) + offy;
        const float pxx = (float)(wo - 1 + kx) + offx;
        const float y0f = floorf(py), x0f = floorf(pxx);
        const float wy = py - y0f, wx = pxx - x0f;
        const int y0 = (int)y0f, x0 = (int)x0f;
        const int y1 = y0 + 1,   x1 = x0 + 1;
        const float vy0 = (y0 >= 0 && y0 < H_) ? 1.f : 0.f;
        const float vy1 = (y1 >= 0 && y1 < H_) ? 1.f : 0.f;
        const float vx0 = (x0 >= 0 && x0 < W_) ? 1.f : 0.f;
        const float vx1 = (x1 >= 0 && x1 < W_) ? 1.f : 0.f;
        f32x4 wv;
        wv[0] = (1.f - wy) * (1.f - wx) * vy0 * vx0;
        wv[1] = (1.f - wy) * wx         * vy0 * vx1;
        wv[2] = wy         * (1.f - wx) * vy1 * vx0;
        wv[3] = wy         * wx         * vy1 * vx1;
        const int y0c = min(max(y0, 0), H_ - 1);
        const int y1c = min(max(y1, 0), H_ - 1);
        const int x0c = min(max(x0, 0), W_ - 1);
        const int x1c = min(max(x1, 0), W_ - 1);
        t_pA[e] = (uint32_t)(y0c * W_ + x0c) | ((uint32_t)(y0c * W_ + x1c) << 16);
        t_pB[e] = (uint32_t)(y1c * W_ + x0c) | ((uint32_t)(y1c * W_ + x1c) << 16);
        t_wv[e] = wv;
    }
    __syncthreads();

    f32x4 acc00 = (f32x4)0.f, acc01 = (f32x4)0.f;
    f32x4 acc10 = (f32x4)0.f, acc11 = (f32x4)0.f;

    const int cog = wave >> 1;           // co-32 group (0..7)
    const int pxg = wave & 1;            // px-32 group
    const int m_l = lane & 15;

    // A-frag bases: cofrag = cog*2 + mt ; offset ((cofrag*8+ch)*9+kk)*512 shorts
    const short* af0b = wfr + ((size_t)(cog * 2 + 0) * 8) * 9 * 512 + lane * 8;
    const short* af1b = wfr + ((size_t)(cog * 2 + 1) * 8) * 9 * 512 + lane * 8;
    // B-frag bases: pxfrag = pxg*2 + nt
    const short* bf0b = &colsF[((pxg * 2 + 0) * 9) * 512 + lane * 8];
    const short* bf1b = &colsF[((pxg * 2 + 1) * 9) * 512 + lane * 8];

    // staging ids: thread -> (px, ch-octet, tap-replica)  [identical to r9]
    const int soct = t & 3;              // channel octet (8 ch)
    const int spx  = (t >> 2) & 63;      // px
    const int srep = t >> 8;             // 0..3: taps {srep, srep+4, srep+8}
    const char* xq = (const char*)xT + ((size_t)b << 21) + soct * 16;
    // staging write slot (B-frag order): frag = (spx>>4)*9 + kk, lane-slot
    short* const cw_base = &colsF[((spx >> 4) * 9) * 512 + ((spx & 15) + (soct << 4)) * 8];

    for (int ch = 0; ch < 8; ++ch) {
        // ---- stage: 4 coalesced 16B corner loads per tap ----
        const char* xc = xq + ch * 64;
#pragma unroll
        for (int jj = 0; jj < 3; ++jj) {
            const int kk = srep + jj * 4;
            if (kk < KK_) {
                const int e  = kk * 64 + spx;
                const uint32_t pA = t_pA[e];
                const uint32_t pB = t_pB[e];
                const f32x4    wv = t_wv[e];
                short8 s00, s01, s10, s11;
                __builtin_memcpy(&s00, xc + (size_t)(pA & 0xFFFFu) * 512, 16);
                __builtin_memcpy(&s01, xc + (size_t)(pA >> 16)     * 512, 16);
                __builtin_memcpy(&s10, xc + (size_t)(pB & 0xFFFFu) * 512, 16);
                __builtin_memcpy(&s11, xc + (size_t)(pB >> 16)     * 512, 16);
                short8 vs;
#pragma unroll
                for (int j = 0; j < 8; ++j) {
                    const float v = wv[0] * bf2f(s00[j]) + wv[1] * bf2f(s01[j])
                                  + wv[2] * bf2f(s10[j]) + wv[3] * bf2f(s11[j]);
                    vs[j] = f2bf(v);
                }
                *reinterpret_cast<short8*>(cw_base + kk * 512) = vs;
            }
        }
        __syncthreads();

        // ---- MFMA over 9 k-steps: 2 coalesced af + 2 LDS bf + 4 MFMA ----
        const short* a0 = af0b + (size_t)ch * 9 * 512;
        const short* a1 = af1b + (size_t)ch * 9 * 512;
#pragma unroll
        for (int kk = 0; kk < 9; ++kk) {
            short8 af0, af1, bf0, bf1;
            __builtin_memcpy(&af0, a0 + kk * 512, 16);
            __builtin_memcpy(&af1, a1 + kk * 512, 16);
            __builtin_memcpy(&bf0, bf0b + kk * 512, 16);
            __builtin_memcpy(&bf1, bf1b + kk * 512, 16);
            acc00 = __builtin_amdgcn_mfma_f32_16x16x32_bf16(af0, bf0, acc00, 0, 0, 0);
            acc01 = __builtin_amdgcn_mfma_f32_16x16x32_bf16(af0, bf1, acc01, 0, 0, 0);
            acc10 = __builtin_amdgcn_mfma_f32_16x16x32_bf16(af1, bf0, acc10, 0, 0, 0);
            acc11 = __builtin_amdgcn_mfma_f32_16x16x32_bf16(af1, bf1, acc11, 0, 0, 0);
        }
        __syncthreads();
    }

    // ---- epilogue: D col=lane&15 (px), row=(lane>>4)*4+r (co) ----
    const int r0 = (lane >> 4) << 2;
    const int co_b = cog * 32;
    const int px_b = pxg * 32;
#pragma unroll
    for (int r = 0; r < 4; ++r) {
        {   // mt = 0
            const int co = co_b + r0 + r;
            const float bv = bias[co];
            float* orow = out + ((size_t)(b * CO_ + co) * H_ + ho) * W_;
            orow[px_b + m_l]      = acc00[r] + bv;
            orow[px_b + 16 + m_l] = acc01[r] + bv;
        }
        {   // mt = 1
            const int co = co_b + 16 + r0 + r;
            const float bv = bias[co];
            float* orow = out + ((size_t)(b * CO_ + co) * H_ + ho) * W_;
            orow[px_b + m_l]      = acc10[r] + bv;
            orow[px_b + 16 + m_l] = acc11[r] + bv;
        }
    }
}

// ================= fallback (round-6 proven path, ws < 18 MB) =================
#define PADK 296
__global__ __launch_bounds__(256) void w2bf_fb(const float* __restrict__ w,
                                               short* __restrict__ wb, int n8) {
    const int i = blockIdx.x * 256 + threadIdx.x;
    if (i >= n8) return;
    const f32x4 a = *reinterpret_cast<const f32x4*>(w + (size_t)i * 8);
    const f32x4 bq = *reinterpret_cast<const f32x4*>(w + (size_t)i * 8 + 4);
    short8 v;
#pragma unroll
    for (int j = 0; j < 4; ++j) { v[j] = f2bf(a[j]); v[j + 4] = f2bf(bq[j]); }
    *reinterpret_cast<short8*>(wb + (size_t)i * 8) = v;
}

__global__ __launch_bounds__(512, 2) void dcn_mfma_fb(
    const float* __restrict__ x,
    const float* __restrict__ offset,
    const short* __restrict__ wbf,
    const float* __restrict__ bias,
    float* __restrict__ out)
{
    __shared__ uint32_t t_oab[KK_ * 64];
    __shared__ f32x4    t_wv[KK_ * 64];
    __shared__ short    colsf[64 * PADK];

    const int bid = blockIdx.x;
    const int ho  = bid & 63;
    const int b   = bid >> 6;
    const int t    = threadIdx.x;
    const int lane = t & 63;
    const int wave = t >> 6;

    for (int e = t; e < KK_ * 64; e += 512) {
        const int kk = e >> 6;
        const int wo = e & 63;
        const int ky = kk / 3, kx = kk % 3;
        const float offy = offset[(((b * 18) + kk * 2 + 0) * 64 + ho) * 64 + wo];
        const float offx = offset[(((b * 18) + kk * 2 + 1) * 64 + ho) * 64 + wo];
        const float py  = (float)(ho - 1 + ky) + offy;
        const float pxx = (float)(wo - 1 + kx) + offx;
        const float y0f = floorf(py), x0f = floorf(pxx);
        const float wy = py - y0f, wx = pxx - x0f;
        const int y0 = (int)y0f, x0 = (int)x0f;
        const int y1 = y0 + 1,   x1 = x0 + 1;
        const float vy0 = (y0 >= 0 && y0 < H_) ? 1.f : 0.f;
        const float vy1 = (y1 >= 0 && y1 < H_) ? 1.f : 0.f;
        const float vx0 = (x0 >= 0 && x0 < W_) ? 1.f : 0.f;
        const float vx1 = (x1 >= 0 && x1 < W_) ? 1.f : 0.f;
        const float wv0 = (1.f - wy) * (1.f - wx) * vy0 * vx0;
        const float wv1 = (1.f - wy) * wx         * vy0 * vx1;
        const float wv2 = wy         * (1.f - wx) * vy1 * vx0;
        const float wv3 = wy         * wx         * vy1 * vx1;
        const int y0c = min(max(y0, 0), H_ - 1);
        const int y1c = min(max(y1, 0), H_ - 1);
        const int x0c = min(max(x0, 0), W_ - 1);
        const int x1c = min(max(x1, 0), W_ - 1);
        const int pb  = min(max(x0, 0), W_ - 2);
        const float sA0 = (x0c == pb)     ? 1.f : 0.f;
        const float sB0 = (x1c == pb)     ? 1.f : 0.f;
        const float sA1 = (x0c == pb + 1) ? 1.f : 0.f;
        const float sB1 = (x1c == pb + 1) ? 1.f : 0.f;
        f32x4 wv;
        wv[0] = sA0 * wv0 + sB0 * wv1;
        wv[1] = sA1 * wv0 + sB1 * wv1;
        wv[2] = sA0 * wv2 + sB0 * wv3;
        wv[3] = sA1 * wv2 + sB1 * wv3;
        t_oab[e] = (uint32_t)((y0c * W_ + pb) * 4) |
                   ((uint32_t)((y1c * W_ + pb) * 4) << 16);
        t_wv[e] = wv;
    }
    __syncthreads();

    f32x4 acc[4][2];
#pragma unroll
    for (int i = 0; i < 4; ++i) { acc[i][0] = (f32x4)0.f; acc[i][1] = (f32x4)0.f; }

    const int wm = wave >> 1;
    const int wn = wave & 1;
    const int co0 = __builtin_amdgcn_readfirstlane(wm * 64);
    const int px0 = __builtin_amdgcn_readfirstlane(wn * 32);
    const int wqs = __builtin_amdgcn_readfirstlane(wave);
    const int m_l = lane & 15;
    const int k_l = (lane >> 4) << 3;

    const short* wrow[4];
#pragma unroll
    for (int mt = 0; mt < 4; ++mt)
        wrow[mt] = wbf + (size_t)(co0 + mt * 16 + m_l) * (C_ * KK_);

    for (int c0 = 0; c0 < C_; c0 += 32) {
        const char* xp[4];
#pragma unroll
        for (int dc = 0; dc < 4; ++dc)
            xp[dc] = (const char*)(x + ((size_t)(b * C_ + c0 + 4 * wqs + dc) << 12));
#pragma unroll
        for (int j = 0; j < 9; ++j) {
            short vs[4];
#pragma unroll
            for (int jj = 0; jj < 4; ++jj) {
                const int idx = j * 4 + jj;
                const int dc  = idx / 9;
                const int kk  = idx % 9;
                const uint32_t oab = t_oab[kk * 64 + lane];
                const f32x4    wv  = t_wv[kk * 64 + lane];
                f32x2 lo, hi;
                __builtin_memcpy(&lo, xp[dc] + (oab & 0xFFFFu), 8);
                __builtin_memcpy(&hi, xp[dc] + (oab >> 16), 8);
                vs[jj] = f2bf(wv[0] * lo[0] + wv[1] * lo[1] +
                              wv[2] * hi[0] + wv[3] * hi[1]);
            }
            short* cw = &colsf[lane * PADK + (wave * 9 + j) * 4];
            cw[0] = vs[0]; cw[1] = vs[1]; cw[2] = vs[2]; cw[3] = vs[3];
        }
        __syncthreads();
#pragma unroll
        for (int s = 0; s < 9; ++s) {
            const int krow = s * 32 + k_l;
            const short8 bfA = *reinterpret_cast<const short8*>(
                &colsf[(px0 + m_l) * PADK + krow]);
            const short8 bfB = *reinterpret_cast<const short8*>(
                &colsf[(px0 + 16 + m_l) * PADK + krow]);
            const int kglob = c0 * 9 + krow;
#pragma unroll
            for (int mt = 0; mt < 4; ++mt) {
                const short8 af = *reinterpret_cast<const short8*>(wrow[mt] + kglob);
                acc[mt][0] = __builtin_amdgcn_mfma_f32_16x16x32_bf16(
                    af, bfA, acc[mt][0], 0, 0, 0);
                acc[mt][1] = __builtin_amdgcn_mfma_f32_16x16x32_bf16(
                    af, bfB, acc[mt][1], 0, 0, 0);
            }
        }
        __syncthreads();
    }

    const int r0 = (lane >> 4) << 2;
#pragma unroll
    for (int mt = 0; mt < 4; ++mt) {
#pragma unroll
        for (int r = 0; r < 4; ++r) {
            const int co = co0 + mt * 16 + r0 + r;
            const float bv = bias[co];
            float* orow = out + ((size_t)(b * CO_ + co) * H_ + ho) * W_;
            orow[px0 + m_l]      = acc[mt][0][r] + bv;
            orow[px0 + 16 + m_l] = acc[mt][1][r] + bv;
        }
    }
}

extern "C" void kernel_launch(void* const* d_in, const int* in_sizes, int n_in,
                              void* d_out, int out_size, void* d_ws, size_t ws_size,
                              hipStream_t stream) {
    const float* x      = (const float*)d_in[0];
    const float* offset = (const float*)d_in[1];
    const float* weight = (const float*)d_in[2];
    const float* bias   = (const float*)d_in[3];
    float* out = (float*)d_out;
    (void)in_sizes; (void)n_in; (void)out_size;

    const size_t WPM_BYTES = (size_t)CO_ * C_ * KK_ * 2;          // 1,179,648
    const size_t XT_BYTES  = (size_t)B_ * H_ * W_ * C_ * 2;       // 16,777,216

    if (ws_size >= WPM_BYTES + XT_BYTES) {
        short* wfr = (short*)d_ws;
        short* xT  = (short*)((char*)d_ws + WPM_BYTES);
        hipLaunchKernelGGL(wperm_frag, dim3(288), dim3(256), 0, stream, weight, wfr);
        hipLaunchKernelGGL(xpose,      dim3(512), dim3(256), 0, stream, x, xT);
        hipLaunchKernelGGL(dcn_mfma6,  dim3(512), dim3(1024), 0, stream,
                           xT, offset, wfr, bias, out);
    } else {
        short* wbf = (short*)d_ws;   // 1.18 MB
        hipLaunchKernelGGL(w2bf_fb, dim3(288), dim3(256), 0, stream,
                           weight, wbf, 73728);
        hipLaunchKernelGGL(dcn_mfma_fb, dim3(512), dim3(512), 0, stream,
                           x, offset, wbf, bias, out);
    }
}